// Round 2
// baseline (329.813 us; speedup 1.0000x reference)
//
#include <hip/hip_runtime.h>
#include <cstdint>
#include <cstddef>

#define NB 8192        // buckets: loss>=0 so bits>>18 = sign0 + exp(8) + 5 mantissa bits
#define TH 1024
#define GRID 512       // 2 blocks/CU * 256 CU

__device__ __forceinline__ float bce_loss(float x, float t) {
  // stable BCE-with-logits, fast transcendentals (err ~1e-6 << 2.5e-2 threshold)
  float u = __expf(-fabsf(x));
  return fmaxf(x, 0.0f) - x * t + __logf(1.0f + u);
}

__device__ __forceinline__ float bucket_mid(unsigned int b) {
  // arithmetic midpoint of bucket [b<<18, (b+1)<<18).
  // NOTE: for b >= 8160 this bit pattern is Inf/NaN — only used for buckets
  // with nonzero count (real losses are finite, <~7).
  return __uint_as_float((b << 18) | 0x20000u);
}

__device__ __forceinline__ void proc1(float x, float t, unsigned int* hh) {
  float l = fmaxf(bce_loss(x, t), 0.0f);  // guard fast-math sign
  atomicAdd(&hh[__float_as_uint(l) >> 18], 1u);
}

__device__ __forceinline__ void proc4(const float4& x, const float4& t,
                                      unsigned int* hh) {
  proc1(x.x, t.x, hh);
  proc1(x.y, t.y, hh);
  proc1(x.z, t.z, hh);
  proc1(x.w, t.w, hh);
}

// ---------------- zero hist[NB] + ticket counter at hist[NB] -------------
__global__ void init_kernel(unsigned int* __restrict__ z) {
  unsigned int i = blockIdx.x * 1024u + threadIdx.x;
  if (i <= NB) z[i] = 0u;
}

// ---------------- fused: histogram + last-block suffix-scan --------------
__global__ __launch_bounds__(TH, 8) void hist_scan_kernel(
    const float* __restrict__ pred, const float* __restrict__ targ,
    unsigned int N, unsigned long long K,
    unsigned int* __restrict__ hist, float* __restrict__ out) {
  // 2 lane-parity replicas: same-address LDS-atomic serialization is a
  // within-wave effect, so split lanes by (tid&1), not by wave. Replicas of
  // one bucket are 32KB apart -> same bank, but 2-way conflicts are free.
  __shared__ __align__(16) unsigned int h[2][NB];  // exactly 64 KB -> 2 blk/CU
  const int tid = threadIdx.x;

  for (int i = tid; i < 2 * NB; i += TH) ((unsigned int*)h)[i] = 0u;
  __syncthreads();

  unsigned int* hh = h[tid & 1];

  const unsigned int n4 = N >> 2;
  const float4* p4 = (const float4*)pred;
  const float4* t4 = (const float4*)targ;
  const unsigned int stride = gridDim.x * blockDim.x;
  unsigned int i = blockIdx.x * blockDim.x + tid;

  // 4x unrolled grid-stride: 8 outstanding dwordx4 loads per wave -> MLP.
  // __launch_bounds__(1024,8) caps VGPR at 64 so 2 blocks/CU survive.
  for (; i + 3u * stride < n4; i += 4u * stride) {
    float4 x0 = p4[i];
    float4 x1 = p4[i + stride];
    float4 x2 = p4[i + 2u * stride];
    float4 x3 = p4[i + 3u * stride];
    float4 t0 = t4[i];
    float4 t1 = t4[i + stride];
    float4 t2 = t4[i + 2u * stride];
    float4 t3 = t4[i + 3u * stride];
    proc4(x0, t0, hh);
    proc4(x1, t1, hh);
    proc4(x2, t2, hh);
    proc4(x3, t3, hh);
  }
  for (; i < n4; i += stride) {
    float4 x = p4[i];
    float4 t = t4[i];
    proc4(x, t, hh);
  }
  if (blockIdx.x == 0) {  // tail (N % 4)
    for (unsigned int k = (n4 << 2) + tid; k < N; k += TH) {
      proc1(pred[k], targ[k], hh);
    }
  }
  __syncthreads();

  // ~400 nonzero buckets/block -> cheap global flush
  for (int b = tid; b < NB; b += TH) {
    unsigned int v = h[0][b] + h[1][b];
    if (v) atomicAdd(&hist[b], v);
  }

  // ---- ticket: last block to arrive scans the global histogram ----------
  __threadfence();            // release: flush atomics visible before ticket
  __syncthreads();            // all flush loop iterations done; h now dead
  if (tid == 0) h[0][0] = atomicAdd(&hist[NB], 1u);  // broadcast via dead LDS
  __syncthreads();
  unsigned int ticket = h[0][0];
  if (ticket != gridDim.x - 1) return;   // whole block exits together

  __threadfence();            // acquire side
  __syncthreads();            // everyone has read ticket; safe to reuse h
  // reuse dead histogram LDS for the scan arrays (LDS stays 64 KB)
  unsigned long long* cs = (unsigned long long*)&h[0][0];   // 8 KB
  double* ss = (double*)&h[0][2048];                        // 8 KB, 8-aligned

  unsigned int c[8];          // 1024 threads * 8 buckets = 8192
  unsigned long long cnt = 0;
  double wsum = 0.0;
#pragma unroll
  for (int j = 0; j < 8; j++) {
    c[j] = __hip_atomic_load(&hist[8 * tid + j], __ATOMIC_RELAXED,
                             __HIP_MEMORY_SCOPE_AGENT);
    cnt += c[j];
    // guard: bucket_mid of empty high buckets is Inf/NaN; 0*NaN would poison
    if (c[j]) wsum += (double)c[j] * (double)bucket_mid(8 * tid + j);
  }
  cs[tid] = cnt;
  ss[tid] = wsum;
  __syncthreads();
  // inclusive suffix sum over threads
  for (int off = 1; off < TH; off <<= 1) {
    unsigned long long tc = (tid + off < TH) ? cs[tid + off] : 0ULL;
    double td = (tid + off < TH) ? ss[tid + off] : 0.0;
    __syncthreads();
    cs[tid] += tc;
    ss[tid] += td;
    __syncthreads();
  }
  unsigned long long ab = (tid < TH - 1) ? cs[tid + 1] : 0ULL;  // strictly above
  double wab = (tid < TH - 1) ? ss[tid + 1] : 0.0;
  for (int j = 7; j >= 0; j--) {
    unsigned long long ge = ab + c[j];
    if (ab < K && ge >= K) {  // exactly one (tid,j) satisfies; c[j] >= 1 here
      unsigned long long rem = K - ab;
      double total = wab + (double)rem * (double)bucket_mid(8 * tid + j);
      *out = (float)(total / (double)K);
    }
    ab = ge;
    if (c[j]) wab += (double)c[j] * (double)bucket_mid(8 * tid + j);
  }
}

extern "C" void kernel_launch(void* const* d_in, const int* in_sizes, int n_in,
                              void* d_out, int out_size, void* d_ws,
                              size_t ws_size, hipStream_t stream) {
  const float* pred = (const float*)d_in[0];
  const float* targ = (const float*)d_in[1];
  unsigned int N = (unsigned int)in_sizes[0];
  unsigned long long K = (unsigned long long)(0.25 * (double)N);
  if (K < 1) K = 1;

  unsigned int* hist = (unsigned int*)d_ws;  // NB+1 uints (last = ticket)
  float* out = (float*)d_out;

  init_kernel<<<(NB + 1024) / 1024, 1024, 0, stream>>>(hist);
  hist_scan_kernel<<<GRID, TH, 0, stream>>>(pred, targ, N, K, hist, out);
}

// Round 3
// 313.222 us; speedup vs baseline: 1.0530x; 1.0530x over previous
//
#include <hip/hip_runtime.h>
#include <cstdint>
#include <cstddef>

#define NB 8192        // buckets: loss>=0 so bits>>18 = sign0 + exp(8) + 5 mantissa bits
#define TH 1024
#define GRID 512       // 2 blocks/CU * 256 CU

__device__ __forceinline__ float bce_loss(float x, float t) {
  // stable BCE-with-logits, fast transcendentals (err ~1e-6 << 2.5e-2 threshold)
  float u = __expf(-fabsf(x));
  return fmaxf(x, 0.0f) - x * t + __logf(1.0f + u);
}

__device__ __forceinline__ float bucket_mid(unsigned int b) {
  // arithmetic midpoint of bucket [b<<18, (b+1)<<18).
  // NOTE: for b >= 8160 this bit pattern is Inf/NaN — only used for buckets
  // with nonzero count (real losses are finite, <~7).
  return __uint_as_float((b << 18) | 0x20000u);
}

// ---------------- zero hist[NB] + ticket counter at hist[NB] -------------
__global__ void init_kernel(unsigned int* __restrict__ z) {
  unsigned int i = blockIdx.x * 1024u + threadIdx.x;
  if (i <= NB) z[i] = 0u;
}

// ---------------- fused: histogram + last-block suffix-scan --------------
// Hot loop is EXACTLY the proven 44us round-0 structure (VGPR=12 regime):
// single grid-stride float4 loop, wave-parity LDS replicas, no min-waves bound.
__global__ __launch_bounds__(TH) void hist_scan_kernel(
    const float* __restrict__ pred, const float* __restrict__ targ,
    unsigned int N, unsigned long long K,
    unsigned int* __restrict__ hist, float* __restrict__ out) {
  __shared__ unsigned int h[2][NB];  // 2 replicas: halves same-address pressure
  const int tid = threadIdx.x;
  for (int i = tid; i < 2 * NB; i += TH) ((unsigned int*)h)[i] = 0u;
  __syncthreads();
  unsigned int* hh = h[(tid >> 6) & 1];

  const unsigned int n4 = N >> 2;
  const float4* p4 = (const float4*)pred;
  const float4* t4 = (const float4*)targ;
  const unsigned int stride = gridDim.x * blockDim.x;
  for (unsigned int i = blockIdx.x * blockDim.x + tid; i < n4; i += stride) {
    float4 x = p4[i];
    float4 t = t4[i];
    float l;
    unsigned int b;
    // clamp: loss is mathematically > 0; guard fast-math edge to keep sign=0
    l = fmaxf(bce_loss(x.x, t.x), 0.0f); b = __float_as_uint(l) >> 18; atomicAdd(&hh[b], 1u);
    l = fmaxf(bce_loss(x.y, t.y), 0.0f); b = __float_as_uint(l) >> 18; atomicAdd(&hh[b], 1u);
    l = fmaxf(bce_loss(x.z, t.z), 0.0f); b = __float_as_uint(l) >> 18; atomicAdd(&hh[b], 1u);
    l = fmaxf(bce_loss(x.w, t.w), 0.0f); b = __float_as_uint(l) >> 18; atomicAdd(&hh[b], 1u);
  }
  if (blockIdx.x == 0) {  // tail (N % 4)
    for (unsigned int k = (n4 << 2) + tid; k < N; k += TH) {
      float l = fmaxf(bce_loss(pred[k], targ[k]), 0.0f);
      atomicAdd(&hh[__float_as_uint(l) >> 18], 1u);
    }
  }
  __syncthreads();

  // ~400 nonzero buckets/block -> cheap global flush
  for (int b = tid; b < NB; b += TH) {
    unsigned int v = h[0][b] + h[1][b];
    if (v) atomicAdd(&hist[b], v);
  }

  // ---- ticket: last block to arrive scans the global histogram ----------
  __threadfence();            // release: flush atomics visible before ticket
  __syncthreads();            // all flush iterations done; h now dead
  if (tid == 0) h[0][0] = atomicAdd(&hist[NB], 1u);  // broadcast via dead LDS
  __syncthreads();
  unsigned int ticket = h[0][0];
  if (ticket != gridDim.x - 1) return;   // whole block exits together

  __threadfence();            // acquire side
  __syncthreads();            // everyone has read ticket; safe to reuse h
  // reuse dead histogram LDS for the scan arrays (LDS stays 64 KB)
  unsigned long long* cs = (unsigned long long*)&h[0][0];   // 8 KB
  double* ss = (double*)&h[0][2048];                        // 8 KB, 8-aligned

  unsigned int c[8];          // 1024 threads * 8 buckets = 8192
  unsigned long long cnt = 0;
  double wsum = 0.0;
#pragma unroll
  for (int j = 0; j < 8; j++) {
    c[j] = __hip_atomic_load(&hist[8 * tid + j], __ATOMIC_RELAXED,
                             __HIP_MEMORY_SCOPE_AGENT);
    cnt += c[j];
    // guard: bucket_mid of empty high buckets is Inf/NaN; 0*NaN would poison
    if (c[j]) wsum += (double)c[j] * (double)bucket_mid(8 * tid + j);
  }
  cs[tid] = cnt;
  ss[tid] = wsum;
  __syncthreads();
  // inclusive suffix sum over threads
  for (int off = 1; off < TH; off <<= 1) {
    unsigned long long tc = (tid + off < TH) ? cs[tid + off] : 0ULL;
    double td = (tid + off < TH) ? ss[tid + off] : 0.0;
    __syncthreads();
    cs[tid] += tc;
    ss[tid] += td;
    __syncthreads();
  }
  unsigned long long ab = (tid < TH - 1) ? cs[tid + 1] : 0ULL;  // strictly above
  double wab = (tid < TH - 1) ? ss[tid + 1] : 0.0;
  for (int j = 7; j >= 0; j--) {
    unsigned long long ge = ab + c[j];
    if (ab < K && ge >= K) {  // exactly one (tid,j) satisfies; c[j] >= 1 here
      unsigned long long rem = K - ab;
      double total = wab + (double)rem * (double)bucket_mid(8 * tid + j);
      *out = (float)(total / (double)K);
    }
    ab = ge;
    if (c[j]) wab += (double)c[j] * (double)bucket_mid(8 * tid + j);
  }
}

extern "C" void kernel_launch(void* const* d_in, const int* in_sizes, int n_in,
                              void* d_out, int out_size, void* d_ws,
                              size_t ws_size, hipStream_t stream) {
  const float* pred = (const float*)d_in[0];
  const float* targ = (const float*)d_in[1];
  unsigned int N = (unsigned int)in_sizes[0];
  unsigned long long K = (unsigned long long)(0.25 * (double)N);
  if (K < 1) K = 1;

  unsigned int* hist = (unsigned int*)d_ws;  // NB+1 uints (last = ticket)
  float* out = (float*)d_out;

  init_kernel<<<(NB + 1024) / 1024, 1024, 0, stream>>>(hist);
  hist_scan_kernel<<<GRID, TH, 0, stream>>>(pred, targ, N, K, hist, out);
}

// Round 4
// 151.612 us; speedup vs baseline: 2.1754x; 2.0659x over previous
//
#include <hip/hip_runtime.h>
#include <cstdint>
#include <cstddef>

#define NB 8192        // buckets: loss>=0 so bits>>18 = sign0 + exp(8) + 5 mantissa bits
#define TH 1024
#define GRID 512       // 2 blocks/CU * 256 CU

__device__ __forceinline__ float bce_loss(float x, float t) {
  // stable BCE-with-logits, fast transcendentals (err ~1e-6 << 2.5e-2 threshold)
  float u = __expf(-fabsf(x));
  return fmaxf(x, 0.0f) - x * t + __logf(1.0f + u);
}

__device__ __forceinline__ float bucket_mid(unsigned int b) {
  // arithmetic midpoint of bucket [b<<18, (b+1)<<18).
  // NOTE: for b >= 8160 this bit pattern is Inf/NaN — only used for buckets
  // with nonzero count (real losses are finite, <~7).
  return __uint_as_float((b << 18) | 0x20000u);
}

__device__ __forceinline__ void proc1(float x, float t, unsigned int* hh) {
  // clamp: loss is mathematically > 0; guard fast-math edge to keep sign=0
  float l = fmaxf(bce_loss(x, t), 0.0f);
  atomicAdd(&hh[__float_as_uint(l) >> 18], 1u);
}

__device__ __forceinline__ void proc4(const float4& x, const float4& t,
                                      unsigned int* hh) {
  proc1(x.x, t.x, hh);
  proc1(x.y, t.y, hh);
  proc1(x.z, t.z, hh);
  proc1(x.w, t.w, hh);
}

// ---------------- zero the global histogram ------------------------------
__global__ void init_kernel(unsigned int* __restrict__ z) {
  z[blockIdx.x * 1024 + threadIdx.x] = 0u;
}

// ---------------- single pass: count-only histogram on bits>>18 ----------
// Blocked ownership: each block owns a contiguous ~128KB slice; thread t
// strides by TH float4s (16KB) within it, 4-way unrolled -> 8 outstanding
// dwordx4 loads per wave, all in one 128KB window (round-2's unroll failed
// because grid-stride put the 4 loads 8MB apart).
__global__ __launch_bounds__(TH) void hist_kernel(
    const float* __restrict__ pred, const float* __restrict__ targ,
    unsigned int N, unsigned int* __restrict__ hist) {
  __shared__ unsigned int h[2][NB];  // 2 replicas: halves same-address pressure
  const int tid = threadIdx.x;
  for (int i = tid; i < 2 * NB; i += TH) ((unsigned int*)h)[i] = 0u;
  __syncthreads();
  unsigned int* hh = h[(tid >> 6) & 1];

  const unsigned int n4 = N >> 2;
  const float4* p4 = (const float4*)pred;
  const float4* t4 = (const float4*)targ;
  const unsigned int chunk = (n4 + gridDim.x - 1) / gridDim.x;  // float4s/block
  const unsigned int base = blockIdx.x * chunk;
  const unsigned int end = (base + chunk < n4) ? (base + chunk) : n4;

  unsigned int j = base + tid;
  for (; j + 3u * TH < end; j += 4u * TH) {
    float4 x0 = p4[j];
    float4 x1 = p4[j + TH];
    float4 x2 = p4[j + 2u * TH];
    float4 x3 = p4[j + 3u * TH];
    float4 t0 = t4[j];
    float4 t1 = t4[j + TH];
    float4 t2 = t4[j + 2u * TH];
    float4 t3 = t4[j + 3u * TH];
    proc4(x0, t0, hh);
    proc4(x1, t1, hh);
    proc4(x2, t2, hh);
    proc4(x3, t3, hh);
  }
  for (; j < end; j += TH) {  // slice remainder (none when chunk % 4TH == 0)
    float4 x = p4[j];
    float4 t = t4[j];
    proc4(x, t, hh);
  }
  if (blockIdx.x == 0) {  // global tail (N % 4)
    for (unsigned int k = (n4 << 2) + tid; k < N; k += TH) {
      proc1(pred[k], targ[k], hh);
    }
  }
  __syncthreads();

  // ~400 nonzero buckets/block -> cheap global flush
  for (int b = tid; b < NB; b += TH) {
    unsigned int v = h[0][b] + h[1][b];
    if (v) atomicAdd(&hist[b], v);
  }
}

// ---------------- scan: suffix sums, find threshold, emit mean -----------
__global__ __launch_bounds__(512) void scan_kernel(
    const unsigned int* __restrict__ hist, unsigned long long K,
    float* __restrict__ out) {
  __shared__ unsigned long long cs[512];
  __shared__ double ss[512];
  int tid = threadIdx.x;  // 512 threads * 16 buckets = 8192
  unsigned int c[16];
  unsigned long long cnt = 0;
  double wsum = 0.0;
#pragma unroll
  for (int j = 0; j < 16; j++) {
    c[j] = hist[16 * tid + j];
    cnt += c[j];
    // guard: bucket_mid of empty high buckets is Inf/NaN; 0*NaN would poison
    if (c[j]) wsum += (double)c[j] * (double)bucket_mid(16 * tid + j);
  }
  cs[tid] = cnt;
  ss[tid] = wsum;
  __syncthreads();
  // inclusive suffix sum over threads
  for (int off = 1; off < 512; off <<= 1) {
    unsigned long long t = (tid + off < 512) ? cs[tid + off] : 0ULL;
    double td = (tid + off < 512) ? ss[tid + off] : 0.0;
    __syncthreads();
    cs[tid] += t;
    ss[tid] += td;
    __syncthreads();
  }
  unsigned long long ab = (tid < 511) ? cs[tid + 1] : 0ULL;   // strictly above
  double wab = (tid < 511) ? ss[tid + 1] : 0.0;
  for (int j = 15; j >= 0; j--) {
    unsigned long long ge = ab + c[j];
    if (ab < K && ge >= K) {  // exactly one (tid,j) satisfies; c[j] >= 1 here
      unsigned long long rem = K - ab;
      double total = wab + (double)rem * (double)bucket_mid(16 * tid + j);
      *out = (float)(total / (double)K);
    }
    ab = ge;
    if (c[j]) wab += (double)c[j] * (double)bucket_mid(16 * tid + j);
  }
}

extern "C" void kernel_launch(void* const* d_in, const int* in_sizes, int n_in,
                              void* d_out, int out_size, void* d_ws,
                              size_t ws_size, hipStream_t stream) {
  const float* pred = (const float*)d_in[0];
  const float* targ = (const float*)d_in[1];
  unsigned int N = (unsigned int)in_sizes[0];
  unsigned long long K = (unsigned long long)(0.25 * (double)N);
  if (K < 1) K = 1;

  unsigned int* hist = (unsigned int*)d_ws;  // 32 KB
  float* out = (float*)d_out;

  init_kernel<<<NB / 1024, 1024, 0, stream>>>(hist);
  hist_kernel<<<GRID, TH, 0, stream>>>(pred, targ, N, hist);
  scan_kernel<<<1, 512, 0, stream>>>(hist, K, out);
}